// Round 1
// baseline (184.370 us; speedup 1.0000x reference)
//
#include <hip/hip_runtime.h>
#include <hip/hip_bf16.h>
#include <stdint.h>

typedef short short8 __attribute__((ext_vector_type(8)));
typedef float f32x4 __attribute__((ext_vector_type(4)));

__device__ __forceinline__ void gload16(const void* g, void* l) {
  __builtin_amdgcn_global_load_lds((const __attribute__((address_space(1))) void*)g,
                                   (__attribute__((address_space(3))) void*)l, 16, 0, 0);
}

__device__ __forceinline__ unsigned short f2b(float f) {
  unsigned int x = __float_as_uint(f);
  x += 0x7fffu + ((x >> 16) & 1u);
  return (unsigned short)(x >> 16);
}

// C[i][j] = sum_k A[i][k] * Bt[j][k]   (A, Bt bf16 row-major)
// MODE 0: plain bf16 out. MODE 1: causal exp(s/32) bf16 out (skip upper tiles).
// MODE 2: fp32 out, scaled by inv[row], K-loop bounded causally.
template<int MODE>
__global__ __launch_bounds__(256) void gemm_bt(
    const unsigned short* __restrict__ A, const unsigned short* __restrict__ Bt,
    void* __restrict__ outv, const float* __restrict__ inv,
    int M, int N, int K,
    long long aZ, long long bZ, long long oZ,
    int lda, int ldb, int ldo)
{
  const int z = blockIdx.z;
  const int row0 = blockIdx.y * 128;
  const int col0 = blockIdx.x * 128;
  if (MODE == 1 && col0 > row0 + 127) return;

  const unsigned short* Az = A + (long long)z * aZ;
  const unsigned short* Bz = Bt + (long long)z * bZ;

  __shared__ __align__(16) char lds[32768];  // A tile [128][64] bf16, B tile after 16KB

  const int tid = threadIdx.x;
  const int wave = tid >> 6;
  const int lane = tid & 63;
  const int wr = wave >> 1, wc = wave & 1;

  // staging: chunk ci covers rows ci*8..ci*8+7, lane l -> row ci*8 + (l>>3),
  // source col-group XOR-swizzled so linear LDS dest ends up swizzled (rule #21)
  const int srow = lane >> 3;
  const int sgrp = (lane & 7) ^ srow;

  // fragment read bases
  const int rA = wr * 64 + (lane & 15);
  const int cB = wc * 64 + (lane & 15);
  const int kb = (lane >> 4) * 16;       // byte offset of this lane's 8 elems
  const int xorA = (rA & 7) << 4;
  const int xorB = (cB & 7) << 4;

  f32x4 acc[4][4];
  #pragma unroll
  for (int m = 0; m < 4; ++m)
    #pragma unroll
    for (int n = 0; n < 4; ++n) acc[m][n] = (f32x4)0.0f;

  int kEnd = K;
  if (MODE == 2) kEnd = min(K, row0 + 128);
  const int nkt = kEnd >> 6;

  for (int kt = 0; kt < nkt; ++kt) {
    const int kc = kt * 64;
    #pragma unroll
    for (int i = 0; i < 4; ++i) {
      const int ci = wave * 4 + i;
      gload16(Az + (long long)(row0 + ci * 8 + srow) * lda + kc + sgrp * 8,
              lds + ci * 1024);
      gload16(Bz + (long long)(col0 + ci * 8 + srow) * ldb + kc + sgrp * 8,
              lds + 16384 + ci * 1024);
    }
    __syncthreads();
    #pragma unroll
    for (int ks = 0; ks < 2; ++ks) {
      short8 af[4], bfr[4];
      #pragma unroll
      for (int m = 0; m < 4; ++m)
        af[m] = *(const short8*)(lds + (rA + m * 16) * 128 + ((ks * 64 + kb) ^ xorA));
      #pragma unroll
      for (int n = 0; n < 4; ++n)
        bfr[n] = *(const short8*)(lds + 16384 + (cB + n * 16) * 128 + ((ks * 64 + kb) ^ xorB));
      #pragma unroll
      for (int m = 0; m < 4; ++m)
        #pragma unroll
        for (int n = 0; n < 4; ++n)
          acc[m][n] = __builtin_amdgcn_mfma_f32_16x16x32_bf16(af[m], bfr[n], acc[m][n], 0, 0, 0);
    }
    __syncthreads();
  }

  const int orow = row0 + wr * 64 + ((lane >> 4) << 2);
  const int ocol = col0 + wc * 64 + (lane & 15);
  if (MODE == 2) {
    float* out = (float*)outv + (long long)z * oZ;
    const float* invz = inv + (long long)z * M;
    #pragma unroll
    for (int m = 0; m < 4; ++m)
      #pragma unroll
      for (int r = 0; r < 4; ++r) {
        const int rg = orow + m * 16 + r;
        const float iv = invz[rg];
        #pragma unroll
        for (int n = 0; n < 4; ++n)
          out[(long long)rg * ldo + ocol + n * 16] = acc[m][n][r] * iv;
      }
  } else {
    unsigned short* out = (unsigned short*)outv + (long long)z * oZ;
    #pragma unroll
    for (int m = 0; m < 4; ++m)
      #pragma unroll
      for (int r = 0; r < 4; ++r) {
        const int rg = orow + m * 16 + r;
        #pragma unroll
        for (int n = 0; n < 4; ++n) {
          const int cg = ocol + n * 16;
          float s = acc[m][n][r];
          unsigned short val;
          if (MODE == 1) {
            float p = (cg > rg) ? 0.0f : __expf(s * 0.03125f);
            val = f2b(p);
          } else {
            val = f2b(s);
          }
          out[(long long)rg * ldo + cg] = val;
        }
      }
  }
}

// fp32 -> bf16 convert, 4 elems/thread
__global__ __launch_bounds__(256) void cvt_x(const float* __restrict__ in,
                                             unsigned short* __restrict__ out, int n4) {
  int i = blockIdx.x * 256 + threadIdx.x;
  if (i >= n4) return;
  const float4 f = ((const float4*)in)[i];
  union { unsigned short u[4]; uint2 v; } o;
  o.u[0] = f2b(f.x); o.u[1] = f2b(f.y); o.u[2] = f2b(f.z); o.u[3] = f2b(f.w);
  ((uint2*)out)[i] = o.v;
}

// W [1024][1024] fp32 -> Wt [1024][1024] bf16 (transposed), 3 matrices via z
__global__ __launch_bounds__(256) void cvt_w(
    const float* __restrict__ W0, const float* __restrict__ W1, const float* __restrict__ W2,
    unsigned short* __restrict__ O0, unsigned short* __restrict__ O1, unsigned short* __restrict__ O2) {
  const float* W = blockIdx.z == 0 ? W0 : (blockIdx.z == 1 ? W1 : W2);
  unsigned short* O = blockIdx.z == 0 ? O0 : (blockIdx.z == 1 ? O1 : O2);
  __shared__ float t[32][33];
  const int tx = threadIdx.x, ty = threadIdx.y;
  const int x = blockIdx.x * 32 + tx;
  const int y0 = blockIdx.y * 32;
  #pragma unroll
  for (int i = 0; i < 4; ++i)
    t[ty + i * 8][tx] = W[(long long)(y0 + ty + i * 8) * 1024 + x];
  __syncthreads();
  const int xo = blockIdx.y * 32 + tx;
  const int yo0 = blockIdx.x * 32;
  #pragma unroll
  for (int i = 0; i < 4; ++i)
    O[(long long)(yo0 + ty + i * 8) * 1024 + xo] = f2b(t[tx][ty + i * 8]);
}

// per-row sum of unnormalized P (bf16) -> 1/sum
__global__ __launch_bounds__(256) void rowsum_inv(const unsigned short* __restrict__ P,
                                                  float* __restrict__ inv) {
  const int q = blockIdx.x, b = blockIdx.y;
  const unsigned short* row = P + ((long long)b * 2048 + q) * 2048;
  const int n = ((q >> 7) + 1) << 7;  // sum through end of diagonal block (zeros beyond q)
  float s = 0.f;
  for (int i = threadIdx.x * 8; i < n; i += 256 * 8) {
    uint4 v = *(const uint4*)(row + i);
    unsigned int w[4] = {v.x, v.y, v.z, v.w};
    #pragma unroll
    for (int j = 0; j < 4; ++j) {
      s += __uint_as_float(w[j] << 16);
      s += __uint_as_float(w[j] & 0xffff0000u);
    }
  }
  #pragma unroll
  for (int off = 32; off > 0; off >>= 1) s += __shfl_down(s, off);
  __shared__ float wsum[4];
  const int lane = threadIdx.x & 63, wave = threadIdx.x >> 6;
  if (lane == 0) wsum[wave] = s;
  __syncthreads();
  if (threadIdx.x == 0)
    inv[(long long)b * 2048 + q] = 1.0f / (wsum[0] + wsum[1] + wsum[2] + wsum[3]);
}

extern "C" void kernel_launch(void* const* d_in, const int* in_sizes, int n_in,
                              void* d_out, int out_size, void* d_ws, size_t ws_size,
                              hipStream_t stream) {
  (void)in_sizes; (void)n_in; (void)out_size; (void)ws_size;
  const float* x  = (const float*)d_in[0];
  const float* Wq = (const float*)d_in[1];
  const float* Wk = (const float*)d_in[2];
  const float* Wv = (const float*)d_in[3];
  float* out = (float*)d_out;

  char* ws = (char*)d_ws;
  unsigned short* xb  = (unsigned short*)(ws);               // 8192x1024 bf16 : 16.78 MB
  unsigned short* Wtq = (unsigned short*)(ws + 16777216);    // 1024x1024 bf16 (transposed)
  unsigned short* Wtk = (unsigned short*)(ws + 18874368);
  unsigned short* Wtv = (unsigned short*)(ws + 20971520);
  unsigned short* Qb  = (unsigned short*)(ws + 23068672);    // 8192x1024 bf16
  unsigned short* Kb  = (unsigned short*)(ws + 39845888);    // 8192x1024 bf16
  unsigned short* Vt  = (unsigned short*)(ws + 56623104);    // 4 x 1024x2048 bf16
  unsigned short* P   = (unsigned short*)(ws + 73400320);    // 4 x 2048x2048 bf16 (unnormalized exp)
  float*          invp = (float*)(ws + 106954752);           // 8192 fp32

  // 1. dtype conversions
  cvt_x<<<8192, 256, 0, stream>>>(x, xb, 2097152);
  cvt_w<<<dim3(32, 32, 3), dim3(32, 8), 0, stream>>>(Wq, Wk, Wv, Wtq, Wtk, Wtv);

  // 2. Q = x Wq, K = x Wk  (8192x1024x1024)
  gemm_bt<0><<<dim3(8, 64, 1), 256, 0, stream>>>(xb, Wtq, Qb, nullptr,
      8192, 1024, 1024, 0, 0, 0, 1024, 1024, 1024);
  gemm_bt<0><<<dim3(8, 64, 1), 256, 0, stream>>>(xb, Wtk, Kb, nullptr,
      8192, 1024, 1024, 0, 0, 0, 1024, 1024, 1024);

  // 3. Vt[b] = Wv^T x_b^T  (1024x2048x1024, per batch) -> V transposed for PV
  gemm_bt<0><<<dim3(16, 8, 4), 256, 0, stream>>>(Wtv, xb, Vt, nullptr,
      1024, 2048, 1024, 0, (long long)2048 * 1024, (long long)1024 * 2048, 1024, 1024, 2048);

  // 4. P = exp((Q K^T)/32) with causal mask, unnormalized, bf16 (per batch)
  gemm_bt<1><<<dim3(16, 16, 4), 256, 0, stream>>>(Qb, Kb, P, nullptr,
      2048, 2048, 1024, (long long)2048 * 1024, (long long)2048 * 1024,
      (long long)2048 * 2048, 1024, 1024, 2048);

  // 5. row sums -> reciprocals
  rowsum_inv<<<dim3(2048, 4), 256, 0, stream>>>(P, invp);

  // 6. context = (P Vt^T) * inv[row]  (fp32 out, causal K-bound per block)
  gemm_bt<2><<<dim3(8, 16, 4), 256, 0, stream>>>(P, Vt, out, invp,
      2048, 1024, 2048, (long long)2048 * 2048, (long long)1024 * 2048,
      (long long)2048 * 1024, 2048, 2048, 1024);
}

// Round 2
// 183.362 us; speedup vs baseline: 1.0055x; 1.0055x over previous
//
#include <hip/hip_runtime.h>
#include <hip/hip_bf16.h>
#include <stdint.h>

typedef short short8 __attribute__((ext_vector_type(8)));
typedef float f32x4 __attribute__((ext_vector_type(4)));

__device__ __forceinline__ void gload16(const void* g, void* l) {
  __builtin_amdgcn_global_load_lds((const __attribute__((address_space(1))) void*)g,
                                   (__attribute__((address_space(3))) void*)l, 16, 0, 0);
}

__device__ __forceinline__ unsigned short f2b(float f) {
  unsigned int x = __float_as_uint(f);
  x += 0x7fffu + ((x >> 16) & 1u);
  return (unsigned short)(x >> 16);
}

// C[i][j] = sum_k A[i][k] * Bt[j][k]   (A, Bt bf16 row-major)
// MODE 0: plain bf16 out.
// MODE 1: causal exp(s/32) bf16 out (skip upper tiles) + per-row sums via atomicAdd.
// MODE 2: fp32 out, scaled by 1/sums[row], K-loop bounded causally.
template<int MODE>
__global__ __launch_bounds__(256) void gemm_bt(
    const unsigned short* __restrict__ A, const unsigned short* __restrict__ Bt,
    void* __restrict__ outv, float* __restrict__ sums,
    int M, int N, int K,
    long long aZ, long long bZ, long long oZ,
    int lda, int ldb, int ldo)
{
  const int z = blockIdx.z;
  const int row0 = blockIdx.y * 128;
  const int col0 = blockIdx.x * 128;
  if (MODE == 1 && col0 > row0 + 127) return;

  const unsigned short* Az = A + (long long)z * aZ;
  const unsigned short* Bz = Bt + (long long)z * bZ;

  __shared__ __align__(16) char lds[32768];  // A tile [128][64] bf16, B tile after 16KB

  const int tid = threadIdx.x;
  const int wave = tid >> 6;
  const int lane = tid & 63;
  const int wr = wave >> 1, wc = wave & 1;

  // staging: chunk ci covers rows ci*8..ci*8+7, lane l -> row ci*8 + (l>>3),
  // source col-group XOR-swizzled so linear LDS dest ends up swizzled (rule #21)
  const int srow = lane >> 3;
  const int sgrp = (lane & 7) ^ srow;

  // fragment read bases
  const int rA = wr * 64 + (lane & 15);
  const int cB = wc * 64 + (lane & 15);
  const int kb = (lane >> 4) * 16;       // byte offset of this lane's 8 elems
  const int xorA = (rA & 7) << 4;
  const int xorB = (cB & 7) << 4;

  f32x4 acc[4][4];
  #pragma unroll
  for (int m = 0; m < 4; ++m)
    #pragma unroll
    for (int n = 0; n < 4; ++n) acc[m][n] = (f32x4)0.0f;

  int kEnd = K;
  if (MODE == 2) kEnd = min(K, row0 + 128);
  const int nkt = kEnd >> 6;

  for (int kt = 0; kt < nkt; ++kt) {
    const int kc = kt * 64;
    #pragma unroll
    for (int i = 0; i < 4; ++i) {
      const int ci = wave * 4 + i;
      gload16(Az + (long long)(row0 + ci * 8 + srow) * lda + kc + sgrp * 8,
              lds + ci * 1024);
      gload16(Bz + (long long)(col0 + ci * 8 + srow) * ldb + kc + sgrp * 8,
              lds + 16384 + ci * 1024);
    }
    __syncthreads();
    #pragma unroll
    for (int ks = 0; ks < 2; ++ks) {
      short8 af[4], bfr[4];
      #pragma unroll
      for (int m = 0; m < 4; ++m)
        af[m] = *(const short8*)(lds + (rA + m * 16) * 128 + ((ks * 64 + kb) ^ xorA));
      #pragma unroll
      for (int n = 0; n < 4; ++n)
        bfr[n] = *(const short8*)(lds + 16384 + (cB + n * 16) * 128 + ((ks * 64 + kb) ^ xorB));
      #pragma unroll
      for (int m = 0; m < 4; ++m)
        #pragma unroll
        for (int n = 0; n < 4; ++n)
          acc[m][n] = __builtin_amdgcn_mfma_f32_16x16x32_bf16(af[m], bfr[n], acc[m][n], 0, 0, 0);
    }
    __syncthreads();
  }

  const int orow = row0 + wr * 64 + ((lane >> 4) << 2);
  const int ocol = col0 + wc * 64 + (lane & 15);
  if (MODE == 2) {
    float* out = (float*)outv + (long long)z * oZ;
    const float* sz = sums + (long long)z * M;
    #pragma unroll
    for (int m = 0; m < 4; ++m)
      #pragma unroll
      for (int r = 0; r < 4; ++r) {
        const int rg = orow + m * 16 + r;
        const float iv = 1.0f / sz[rg];
        #pragma unroll
        for (int n = 0; n < 4; ++n)
          out[(long long)rg * ldo + ocol + n * 16] = acc[m][n][r] * iv;
      }
  } else {
    unsigned short* out = (unsigned short*)outv + (long long)z * oZ;
    #pragma unroll
    for (int m = 0; m < 4; ++m)
      #pragma unroll
      for (int r = 0; r < 4; ++r) {
        const int rg = orow + m * 16 + r;
        float rs = 0.f;
        #pragma unroll
        for (int n = 0; n < 4; ++n) {
          const int cg = ocol + n * 16;
          float s = acc[m][n][r];
          float p;
          if (MODE == 1) {
            p = (cg > rg) ? 0.0f : __expf(s * 0.03125f);
            rs += p;
          } else {
            p = s;
          }
          out[(long long)rg * ldo + cg] = f2b(p);
        }
        if (MODE == 1) {
          // reduce across the 16 lanes of this lane-group (same lane>>4)
          #pragma unroll
          for (int off = 1; off < 16; off <<= 1) rs += __shfl_xor(rs, off);
          if ((lane & 15) == 0) atomicAdd(&sums[(long long)z * M + rg], rs);
        }
      }
  }
}

// fp32 -> bf16 convert, 4 elems/thread
__global__ __launch_bounds__(256) void cvt_x(const float* __restrict__ in,
                                             unsigned short* __restrict__ out, int n4) {
  int i = blockIdx.x * 256 + threadIdx.x;
  if (i >= n4) return;
  const float4 f = ((const float4*)in)[i];
  union { unsigned short u[4]; uint2 v; } o;
  o.u[0] = f2b(f.x); o.u[1] = f2b(f.y); o.u[2] = f2b(f.z); o.u[3] = f2b(f.w);
  ((uint2*)out)[i] = o.v;
}

// W [1024][1024] fp32 -> Wt bf16 transposed; 3 matrices (z) into contiguous [3072][1024]
__global__ __launch_bounds__(256) void cvt_w(
    const float* __restrict__ W0, const float* __restrict__ W1, const float* __restrict__ W2,
    unsigned short* __restrict__ O) {
  const float* W = blockIdx.z == 0 ? W0 : (blockIdx.z == 1 ? W1 : W2);
  unsigned short* Oz = O + (long long)blockIdx.z * 1024 * 1024;
  __shared__ float t[32][33];
  const int tx = threadIdx.x, ty = threadIdx.y;
  const int x = blockIdx.x * 32 + tx;
  const int y0 = blockIdx.y * 32;
  #pragma unroll
  for (int i = 0; i < 4; ++i)
    t[ty + i * 8][tx] = W[(long long)(y0 + ty + i * 8) * 1024 + x];
  __syncthreads();
  const int xo = blockIdx.y * 32 + tx;
  const int yo0 = blockIdx.x * 32;
  #pragma unroll
  for (int i = 0; i < 4; ++i)
    Oz[(long long)(yo0 + ty + i * 8) * 1024 + xo] = f2b(t[tx][ty + i * 8]);
}

// Vt[b][d][t] = QKV[b*2048+t][2048+d]  (bf16 transpose of the V section)
__global__ __launch_bounds__(256) void vtrans(const unsigned short* __restrict__ QKV,
                                              unsigned short* __restrict__ Vt) {
  __shared__ unsigned short t[32][33];
  const int tx = threadIdx.x, ty = threadIdx.y;  // 32x8
  const int b = blockIdx.z;
  const int t0 = blockIdx.x * 32;   // token tile
  const int d0 = blockIdx.y * 32;   // d tile
  #pragma unroll
  for (int i = 0; i < 4; ++i)
    t[ty + i * 8][tx] = QKV[(long long)(b * 2048 + t0 + ty + i * 8) * 3072 + 2048 + d0 + tx];
  __syncthreads();
  #pragma unroll
  for (int i = 0; i < 4; ++i)
    Vt[((long long)b * 1024 + d0 + ty + i * 8) * 2048 + t0 + tx] = t[tx][ty + i * 8];
}

extern "C" void kernel_launch(void* const* d_in, const int* in_sizes, int n_in,
                              void* d_out, int out_size, void* d_ws, size_t ws_size,
                              hipStream_t stream) {
  (void)in_sizes; (void)n_in; (void)out_size; (void)ws_size;
  const float* x  = (const float*)d_in[0];
  const float* Wq = (const float*)d_in[1];
  const float* Wk = (const float*)d_in[2];
  const float* Wv = (const float*)d_in[3];
  float* out = (float*)d_out;

  char* ws = (char*)d_ws;
  unsigned short* xb  = (unsigned short*)(ws);               // 8192x1024 bf16 : 16.78 MB
  unsigned short* Wt  = (unsigned short*)(ws + 16777216);    // 3072x1024 bf16 : 6.29 MB
  unsigned short* P   = (unsigned short*)(ws);               // 4x2048x2048 bf16 (reuses xb+Wt, dead by then)
  unsigned short* QKV = (unsigned short*)(ws + 33554432);    // 8192x3072 bf16 : 50.33 MB
  unsigned short* Vt  = (unsigned short*)(ws + 83886080);    // 4x1024x2048 bf16 : 16.78 MB
  float*          sums = (float*)(ws + 100663296);           // 4x2048 fp32

  hipMemsetAsync(sums, 0, 4 * 2048 * sizeof(float), stream);

  // 1. dtype conversions (Wt = [Wq^T; Wk^T; Wv^T] contiguous)
  cvt_x<<<8192, 256, 0, stream>>>(x, xb, 2097152);
  cvt_w<<<dim3(32, 32, 3), dim3(32, 8), 0, stream>>>(Wq, Wk, Wv, Wt);

  // 2. fused QKV = x [8192x1024] . Wt^T [1024x3072] -> [8192][3072]
  gemm_bt<0><<<dim3(24, 64, 1), 256, 0, stream>>>(xb, Wt, QKV, nullptr,
      8192, 3072, 1024, 0, 0, 0, 1024, 1024, 3072);

  // 3. V section -> Vt [b][1024][2048]
  vtrans<<<dim3(64, 32, 4), dim3(32, 8), 0, stream>>>(QKV, Vt);

  // 4. P = exp((Q K^T)/32) causal, unnormalized bf16; row sums accumulated atomically
  gemm_bt<1><<<dim3(16, 16, 4), 256, 0, stream>>>(QKV, QKV + 1024, P, sums,
      2048, 2048, 1024, (long long)2048 * 3072, (long long)2048 * 3072,
      (long long)2048 * 2048, 3072, 3072, 2048);

  // 5. context = (P Vt^T) / rowsum  (fp32 out, causal K-bound per block)
  gemm_bt<2><<<dim3(8, 16, 4), 256, 0, stream>>>(P, Vt, out, sums,
      2048, 1024, 2048, (long long)2048 * 2048, (long long)1024 * 2048,
      (long long)2048 * 1024, 2048, 2048, 1024);
}

// Round 3
// 173.498 us; speedup vs baseline: 1.0627x; 1.0568x over previous
//
#include <hip/hip_runtime.h>
#include <hip/hip_bf16.h>
#include <stdint.h>

typedef short short8 __attribute__((ext_vector_type(8)));
typedef float f32x4 __attribute__((ext_vector_type(4)));

__device__ __forceinline__ void gload16(const void* g, void* l) {
  __builtin_amdgcn_global_load_lds((const __attribute__((address_space(1))) void*)g,
                                   (__attribute__((address_space(3))) void*)l, 16, 0, 0);
}

__device__ __forceinline__ unsigned short f2b(float f) {
  unsigned int x = __float_as_uint(f);
  x += 0x7fffu + ((x >> 16) & 1u);
  return (unsigned short)(x >> 16);
}

// ==================== 256x256 8-phase GEMM ====================
// C[i][j] = sum_k A[i][k]*Bt[j][k], A/Bt bf16 row-major.
// MODE 0: bf16 out. MODE 1: causal exp(s/32) bf16 out + rowsum atomics.
// 512 thr = 8 waves (2M x 4N), wave tile 128x64, BK=64, 2 K-tiles/iter, 8 phases.

#define STG(buf, isB, half, kt) do {                                           \
    const unsigned short* _s = (isB) ? Bz : Az;                                \
    const int _ld = (isB) ? ldb : lda;                                         \
    const int _b0 = (isB) ? col0 : row0;                                       \
    char* _d = lds + (buf) * 65536 + (isB) * 32768 + (half) * 16384;           \
    _Pragma("unroll")                                                          \
    for (int _i = 0; _i < 2; ++_i) {                                           \
      const int _c = wave * 2 + _i;                                            \
      const int _row = (half) * 128 + _c * 8 + srow;                           \
      gload16(_s + (long long)(_b0 + _row) * _ld + (kt) * 64 + sgrp * 8,       \
              _d + _c * 1024);                                                 \
    } } while (0)

#define LDA8(dst, buf, mh) do {                                                \
    _Pragma("unroll")                                                          \
    for (int _m = 0; _m < 4; ++_m) {                                           \
      const int _r = wr * 128 + ((mh) * 4 + _m) * 16 + (lane & 15);            \
      const char* _p = lds + (buf) * 65536 + _r * 128;                         \
      const int _x = (_r & 7) << 4;                                            \
      dst[_m][0] = *(const short8*)(_p + ((kbyte) ^ _x));                      \
      dst[_m][1] = *(const short8*)(_p + ((64 + kbyte) ^ _x));                 \
    } } while (0)

#define LDB4(dst, buf, nh) do {                                                \
    _Pragma("unroll")                                                          \
    for (int _n = 0; _n < 2; ++_n) {                                           \
      const int _r = wc * 64 + ((nh) * 2 + _n) * 16 + (lane & 15);             \
      const char* _p = lds + (buf) * 65536 + 32768 + _r * 128;                 \
      const int _x = (_r & 7) << 4;                                            \
      dst[_n][0] = *(const short8*)(_p + ((kbyte) ^ _x));                      \
      dst[_n][1] = *(const short8*)(_p + ((64 + kbyte) ^ _x));                 \
    } } while (0)

#define MFMA16(mh, nh, av, bv) do {                                            \
    __builtin_amdgcn_s_setprio(1);                                             \
    _Pragma("unroll") for (int _n = 0; _n < 2; ++_n)                           \
    _Pragma("unroll") for (int _m = 0; _m < 4; ++_m)                           \
    _Pragma("unroll") for (int _k = 0; _k < 2; ++_k)                           \
      acc[(mh)*4+_m][(nh)*2+_n] = __builtin_amdgcn_mfma_f32_16x16x32_bf16(     \
          av[_m][_k], bv[_n][_k], acc[(mh)*4+_m][(nh)*2+_n], 0, 0, 0);         \
    __builtin_amdgcn_s_setprio(0);                                             \
  } while (0)

#define BAR() __builtin_amdgcn_s_barrier()
#define VM2() asm volatile("s_waitcnt vmcnt(2)" ::: "memory")
#define VM0() asm volatile("s_waitcnt vmcnt(0)" ::: "memory")

template<int MODE>
__global__ __launch_bounds__(512, 2) void gemm8(
    const unsigned short* __restrict__ A, const unsigned short* __restrict__ Bt,
    void* __restrict__ outv, float* __restrict__ sums,
    int M, int N, int K,
    long long aZ, long long bZ, long long oZ,
    int lda, int ldb, int ldo)
{
  const int z = blockIdx.z;
  const int row0 = blockIdx.y * 256;
  const int col0 = blockIdx.x * 256;
  if (MODE == 1 && col0 > row0 + 255) return;

  const unsigned short* Az = A + (long long)z * aZ;
  const unsigned short* Bz = Bt + (long long)z * bZ;

  __shared__ __align__(16) char lds[131072];  // 2 bufs x (A 32KB + B 32KB)

  const int tid = threadIdx.x;
  const int wave = tid >> 6, lane = tid & 63;
  const int wr = wave >> 2, wc = wave & 3;
  const int srow = lane >> 3, sgrp = (lane & 7) ^ srow;
  const int kbyte = (lane >> 4) * 16;

  const int nt = K >> 7;  // iterations, 2 K-tiles (BK=64) each

  f32x4 acc[8][4];
  #pragma unroll
  for (int m = 0; m < 8; ++m)
    #pragma unroll
    for (int n = 0; n < 4; ++n) acc[m][n] = (f32x4)0.0f;

  short8 a[4][2], b0[2][2], b1[2][2];

  // prologue: full buf0 (K-tile 0) + A-half0 of buf1 (K-tile 1)
  STG(0, 0, 0, 0); STG(0, 0, 1, 0); STG(0, 1, 0, 0); STG(0, 1, 1, 0);
  STG(1, 0, 0, 1);
  VM2(); BAR();

  for (int t = 0; t < nt; ++t) {
    const int c1 = 2 * t + 1;
    const bool pf = (t < nt - 1);
    // ---- K-tile 2t (buf0): quadrant order (mh0,nh0)(mh0,nh1)(mh1,nh1)(mh1,nh0)
    // ph1
    LDA8(a, 0, 0); LDB4(b0, 0, 0);
    STG(1, 0, 1, c1);
    BAR(); MFMA16(0, 0, a, b0); BAR();
    // ph2
    LDB4(b1, 0, 1);
    STG(1, 1, 0, c1);
    BAR(); MFMA16(0, 1, a, b1); BAR();
    // ph3
    LDA8(a, 0, 1);
    STG(1, 1, 1, c1);
    BAR(); MFMA16(1, 1, a, b1); BAR();
    // ph4  (buf1 must be fully landed before ph5)
    LDB4(b0, 0, 0);
    if (pf) STG(0, 0, 0, 2 * t + 2);
    BAR(); MFMA16(1, 0, a, b0);
    if (pf) VM2(); else VM0();
    BAR();
    // ---- K-tile 2t+1 (buf1)
    // ph5
    LDA8(a, 1, 0); LDB4(b0, 1, 0);
    if (pf) STG(0, 0, 1, 2 * t + 2);
    BAR(); MFMA16(0, 0, a, b0); BAR();
    // ph6
    LDB4(b1, 1, 1);
    if (pf) STG(0, 1, 0, 2 * t + 2);
    BAR(); MFMA16(0, 1, a, b1); BAR();
    // ph7
    LDA8(a, 1, 1);
    if (pf) STG(0, 1, 1, 2 * t + 2);
    BAR(); MFMA16(1, 1, a, b1); BAR();
    // ph8  (buf0 must be fully landed before next ph1)
    LDB4(b0, 1, 0);
    if (pf) STG(1, 0, 0, 2 * t + 3);
    BAR(); MFMA16(1, 0, a, b0);
    if (pf) VM2(); else VM0();
    BAR();
  }

  const int orow = row0 + wr * 128 + ((lane >> 4) << 2);
  const int ocol = col0 + wc * 64 + (lane & 15);
  if (MODE == 0) {
    unsigned short* out = (unsigned short*)outv + (long long)z * oZ;
    #pragma unroll
    for (int m = 0; m < 8; ++m)
      #pragma unroll
      for (int r = 0; r < 4; ++r) {
        const int rg = orow + m * 16 + r;
        #pragma unroll
        for (int n = 0; n < 4; ++n)
          out[(long long)rg * ldo + ocol + n * 16] = f2b(acc[m][n][r]);
      }
  } else {
    unsigned short* out = (unsigned short*)outv + (long long)z * oZ;
    #pragma unroll
    for (int m = 0; m < 8; ++m)
      #pragma unroll
      for (int r = 0; r < 4; ++r) {
        const int rg = orow + m * 16 + r;
        float rs = 0.f;
        #pragma unroll
        for (int n = 0; n < 4; ++n) {
          const int cg = ocol + n * 16;
          float p = (cg > rg) ? 0.0f : __expf(acc[m][n][r] * 0.03125f);
          rs += p;
          out[(long long)rg * ldo + cg] = f2b(p);
        }
        #pragma unroll
        for (int off = 1; off < 16; off <<= 1) rs += __shfl_xor(rs, off);
        if ((lane & 15) == 0) atomicAdd(&sums[(long long)z * M + rg], rs);
      }
  }
}

// ==================== 128x128 2-phase GEMM (PV only) ====================
// MODE 2: fp32 out scaled by 1/sums[row], K-loop bounded causally.
template<int MODE>
__global__ __launch_bounds__(256) void gemm_bt(
    const unsigned short* __restrict__ A, const unsigned short* __restrict__ Bt,
    void* __restrict__ outv, float* __restrict__ sums,
    int M, int N, int K,
    long long aZ, long long bZ, long long oZ,
    int lda, int ldb, int ldo)
{
  const int z = blockIdx.z;
  const int row0 = blockIdx.y * 128;
  const int col0 = blockIdx.x * 128;

  const unsigned short* Az = A + (long long)z * aZ;
  const unsigned short* Bz = Bt + (long long)z * bZ;

  __shared__ __align__(16) char lds[32768];

  const int tid = threadIdx.x;
  const int wave = tid >> 6;
  const int lane = tid & 63;
  const int wr = wave >> 1, wc = wave & 1;

  const int srow = lane >> 3;
  const int sgrp = (lane & 7) ^ srow;

  const int rA = wr * 64 + (lane & 15);
  const int cB = wc * 64 + (lane & 15);
  const int kb = (lane >> 4) * 16;
  const int xorA = (rA & 7) << 4;
  const int xorB = (cB & 7) << 4;

  f32x4 acc[4][4];
  #pragma unroll
  for (int m = 0; m < 4; ++m)
    #pragma unroll
    for (int n = 0; n < 4; ++n) acc[m][n] = (f32x4)0.0f;

  int kEnd = K;
  if (MODE == 2) kEnd = min(K, row0 + 128);
  const int nkt = kEnd >> 6;

  for (int kt = 0; kt < nkt; ++kt) {
    const int kc = kt * 64;
    #pragma unroll
    for (int i = 0; i < 4; ++i) {
      const int ci = wave * 4 + i;
      gload16(Az + (long long)(row0 + ci * 8 + srow) * lda + kc + sgrp * 8,
              lds + ci * 1024);
      gload16(Bz + (long long)(col0 + ci * 8 + srow) * ldb + kc + sgrp * 8,
              lds + 16384 + ci * 1024);
    }
    __syncthreads();
    #pragma unroll
    for (int ks = 0; ks < 2; ++ks) {
      short8 af[4], bfr[4];
      #pragma unroll
      for (int m = 0; m < 4; ++m)
        af[m] = *(const short8*)(lds + (rA + m * 16) * 128 + ((ks * 64 + kb) ^ xorA));
      #pragma unroll
      for (int n = 0; n < 4; ++n)
        bfr[n] = *(const short8*)(lds + 16384 + (cB + n * 16) * 128 + ((ks * 64 + kb) ^ xorB));
      #pragma unroll
      for (int m = 0; m < 4; ++m)
        #pragma unroll
        for (int n = 0; n < 4; ++n)
          acc[m][n] = __builtin_amdgcn_mfma_f32_16x16x32_bf16(af[m], bfr[n], acc[m][n], 0, 0, 0);
    }
    __syncthreads();
  }

  const int orow = row0 + wr * 64 + ((lane >> 4) << 2);
  const int ocol = col0 + wc * 64 + (lane & 15);
  float* out = (float*)outv + (long long)z * oZ;
  const float* sz = sums + (long long)z * M;
  #pragma unroll
  for (int m = 0; m < 4; ++m)
    #pragma unroll
    for (int r = 0; r < 4; ++r) {
      const int rg = orow + m * 16 + r;
      const float iv = 1.0f / sz[rg];
      #pragma unroll
      for (int n = 0; n < 4; ++n)
        out[(long long)rg * ldo + ocol + n * 16] = acc[m][n][r] * iv;
    }
}

// fp32 -> bf16 convert, 4 elems/thread
__global__ __launch_bounds__(256) void cvt_x(const float* __restrict__ in,
                                             unsigned short* __restrict__ out, int n4) {
  int i = blockIdx.x * 256 + threadIdx.x;
  if (i >= n4) return;
  const float4 f = ((const float4*)in)[i];
  union { unsigned short u[4]; uint2 v; } o;
  o.u[0] = f2b(f.x); o.u[1] = f2b(f.y); o.u[2] = f2b(f.z); o.u[3] = f2b(f.w);
  ((uint2*)out)[i] = o.v;
}

// W [1024][1024] fp32 -> Wt bf16 transposed; 3 matrices (z) into contiguous [3072][1024]
__global__ __launch_bounds__(256) void cvt_w(
    const float* __restrict__ W0, const float* __restrict__ W1, const float* __restrict__ W2,
    unsigned short* __restrict__ O) {
  const float* W = blockIdx.z == 0 ? W0 : (blockIdx.z == 1 ? W1 : W2);
  unsigned short* Oz = O + (long long)blockIdx.z * 1024 * 1024;
  __shared__ float t[32][33];
  const int tx = threadIdx.x, ty = threadIdx.y;
  const int x = blockIdx.x * 32 + tx;
  const int y0 = blockIdx.y * 32;
  #pragma unroll
  for (int i = 0; i < 4; ++i)
    t[ty + i * 8][tx] = W[(long long)(y0 + ty + i * 8) * 1024 + x];
  __syncthreads();
  const int xo = blockIdx.y * 32 + tx;
  const int yo0 = blockIdx.x * 32;
  #pragma unroll
  for (int i = 0; i < 4; ++i)
    Oz[(long long)(yo0 + ty + i * 8) * 1024 + xo] = f2b(t[tx][ty + i * 8]);
}

// Vt[b][d][t] = QKV[b*2048+t][2048+d]
__global__ __launch_bounds__(256) void vtrans(const unsigned short* __restrict__ QKV,
                                              unsigned short* __restrict__ Vt) {
  __shared__ unsigned short t[32][33];
  const int tx = threadIdx.x, ty = threadIdx.y;  // 32x8
  const int b = blockIdx.z;
  const int t0 = blockIdx.x * 32;
  const int d0 = blockIdx.y * 32;
  #pragma unroll
  for (int i = 0; i < 4; ++i)
    t[ty + i * 8][tx] = QKV[(long long)(b * 2048 + t0 + ty + i * 8) * 3072 + 2048 + d0 + tx];
  __syncthreads();
  #pragma unroll
  for (int i = 0; i < 4; ++i)
    Vt[((long long)b * 1024 + d0 + ty + i * 8) * 2048 + t0 + tx] = t[tx][ty + i * 8];
}

extern "C" void kernel_launch(void* const* d_in, const int* in_sizes, int n_in,
                              void* d_out, int out_size, void* d_ws, size_t ws_size,
                              hipStream_t stream) {
  (void)in_sizes; (void)n_in; (void)out_size; (void)ws_size;
  const float* x  = (const float*)d_in[0];
  const float* Wq = (const float*)d_in[1];
  const float* Wk = (const float*)d_in[2];
  const float* Wv = (const float*)d_in[3];
  float* out = (float*)d_out;

  char* ws = (char*)d_ws;
  unsigned short* xb  = (unsigned short*)(ws);               // 8192x1024 bf16
  unsigned short* Wt  = (unsigned short*)(ws + 16777216);    // 3072x1024 bf16
  unsigned short* P   = (unsigned short*)(ws);               // 4x2048x2048 bf16 (reuses xb+Wt)
  unsigned short* QKV = (unsigned short*)(ws + 33554432);    // 8192x3072 bf16
  unsigned short* Vt  = (unsigned short*)(ws + 83886080);    // 4x1024x2048 bf16
  float*          sums = (float*)(ws + 100663296);           // 4x2048 fp32

  hipMemsetAsync(sums, 0, 4 * 2048 * sizeof(float), stream);

  // 1. dtype conversions
  cvt_x<<<8192, 256, 0, stream>>>(x, xb, 2097152);
  cvt_w<<<dim3(32, 32, 3), dim3(32, 8), 0, stream>>>(Wq, Wk, Wv, Wt);

  // 2. fused QKV = x . Wt^T  [8192][3072]  (8-phase 256^2)
  gemm8<0><<<dim3(12, 32, 1), 512, 0, stream>>>(xb, Wt, QKV, nullptr,
      8192, 3072, 1024, 0, 0, 0, 1024, 1024, 3072);

  // 3. V section -> Vt [b][1024][2048]
  vtrans<<<dim3(64, 32, 4), dim3(32, 8), 0, stream>>>(QKV, Vt);

  // 4. P = exp((Q K^T)/32) causal, unnormalized bf16 + rowsums  (8-phase 256^2)
  gemm8<1><<<dim3(8, 8, 4), 512, 0, stream>>>(QKV, QKV + 1024, P, sums,
      2048, 2048, 1024, (long long)2048 * 3072, (long long)2048 * 3072,
      (long long)2048 * 2048, 3072, 3072, 2048);

  // 5. context = (P Vt^T) / rowsum  (fp32 out, causal K-bound)
  gemm_bt<2><<<dim3(8, 16, 4), 256, 0, stream>>>(P, Vt, out, sums,
      2048, 1024, 2048, (long long)2048 * 2048, (long long)1024 * 2048,
      (long long)2048 * 1024, 2048, 2048, 1024);
}

// Round 4
// 171.955 us; speedup vs baseline: 1.0722x; 1.0090x over previous
//
#include <hip/hip_runtime.h>
#include <hip/hip_bf16.h>
#include <stdint.h>

typedef short short8 __attribute__((ext_vector_type(8)));
typedef float f32x4 __attribute__((ext_vector_type(4)));

__device__ __forceinline__ void gload16(const void* g, void* l) {
  __builtin_amdgcn_global_load_lds((const __attribute__((address_space(1))) void*)g,
                                   (__attribute__((address_space(3))) void*)l, 16, 0, 0);
}

__device__ __forceinline__ unsigned short f2b(float f) {
  unsigned int x = __float_as_uint(f);
  x += 0x7fffu + ((x >> 16) & 1u);
  return (unsigned short)(x >> 16);
}

// ==================== 256x256 8-phase GEMM (deep pipeline) ====================
// C[i][j] = sum_k A[i][k]*Bt[j][k], A/Bt bf16 row-major.
// MODE 0: bf16 out. MODE 1: causal exp(s/32) bf16 out + rowsum atomics.
// 512 thr = 8 waves (2M x 4N), wave tile 128x64, BK=64, 2 K-tiles/iter, 8 phases.
// Staging runs 4-6 phases ahead of use; waits vmcnt(4) at ph4/ph8 only.

#define STG(buf, isB, half, kt) do {                                           \
    const unsigned short* _s = (isB) ? Bz : Az;                                \
    const int _ld = (isB) ? ldb : lda;                                         \
    const int _b0 = (isB) ? col0 : row0;                                       \
    char* _d = lds + (buf) * 65536 + (isB) * 32768 + (half) * 16384;           \
    _Pragma("unroll")                                                          \
    for (int _i = 0; _i < 2; ++_i) {                                           \
      const int _c = wave * 2 + _i;                                            \
      const int _row = (half) * 128 + _c * 8 + srow;                           \
      gload16(_s + (long long)(_b0 + _row) * _ld + (kt) * 64 + sgrp * 8,       \
              _d + _c * 1024);                                                 \
    } } while (0)

#define LDA8(dst, buf, mh) do {                                                \
    _Pragma("unroll")                                                          \
    for (int _m = 0; _m < 4; ++_m) {                                           \
      const int _r = wr * 128 + ((mh) * 4 + _m) * 16 + (lane & 15);            \
      const char* _p = lds + (buf) * 65536 + _r * 128;                         \
      const int _x = (_r & 7) << 4;                                            \
      dst[_m][0] = *(const short8*)(_p + ((kbyte) ^ _x));                      \
      dst[_m][1] = *(const short8*)(_p + ((64 + kbyte) ^ _x));                 \
    } } while (0)

#define LDB4(dst, buf, nh) do {                                                \
    _Pragma("unroll")                                                          \
    for (int _n = 0; _n < 2; ++_n) {                                           \
      const int _r = wc * 64 + ((nh) * 2 + _n) * 16 + (lane & 15);             \
      const char* _p = lds + (buf) * 65536 + 32768 + _r * 128;                 \
      const int _x = (_r & 7) << 4;                                            \
      dst[_n][0] = *(const short8*)(_p + ((kbyte) ^ _x));                      \
      dst[_n][1] = *(const short8*)(_p + ((64 + kbyte) ^ _x));                 \
    } } while (0)

#define MFMA16(mh, nh, av, bv) do {                                            \
    __builtin_amdgcn_s_setprio(1);                                             \
    _Pragma("unroll") for (int _n = 0; _n < 2; ++_n)                           \
    _Pragma("unroll") for (int _m = 0; _m < 4; ++_m)                           \
    _Pragma("unroll") for (int _k = 0; _k < 2; ++_k)                           \
      acc[(mh)*4+_m][(nh)*2+_n] = __builtin_amdgcn_mfma_f32_16x16x32_bf16(     \
          av[_m][_k], bv[_n][_k], acc[(mh)*4+_m][(nh)*2+_n], 0, 0, 0);         \
    __builtin_amdgcn_s_setprio(0);                                             \
  } while (0)

#define BAR() __builtin_amdgcn_s_barrier()
#define VM4() asm volatile("s_waitcnt vmcnt(4)" ::: "memory")
#define VM0() asm volatile("s_waitcnt vmcnt(0)" ::: "memory")

template<int MODE>
__global__ __launch_bounds__(512, 2) void gemm8(
    const unsigned short* __restrict__ A, const unsigned short* __restrict__ Bt,
    void* __restrict__ outv, float* __restrict__ sums,
    int M, int N, int K,
    long long aZ, long long bZ, long long oZ,
    int lda, int ldb, int ldo)
{
  const int z = blockIdx.z;
  const int row0 = blockIdx.y * 256;
  const int col0 = blockIdx.x * 256;
  if (MODE == 1 && col0 > row0 + 255) return;

  const unsigned short* Az = A + (long long)z * aZ;
  const unsigned short* Bz = Bt + (long long)z * bZ;

  __shared__ __align__(16) char lds[131072];  // 2 bufs x (A 32KB + B 32KB)

  const int tid = threadIdx.x;
  const int wave = tid >> 6, lane = tid & 63;
  const int wr = wave >> 2, wc = wave & 3;
  const int srow = lane >> 3, sgrp = (lane & 7) ^ srow;
  const int kbyte = (lane >> 4) * 16;

  const int nt = K >> 7;  // iterations, 2 K-tiles (BK=64) each

  f32x4 acc[8][4];
  #pragma unroll
  for (int m = 0; m < 8; ++m)
    #pragma unroll
    for (int n = 0; n < 4; ++n) acc[m][n] = (f32x4)0.0f;

  short8 a[4][2], b0[2][2], b1[2][2];

  // prologue: buf0 (K-tile 0) fully; buf1.B (K-tile 1)  [12 loads/thread]
  STG(0, 1, 0, 0); STG(0, 1, 1, 0); STG(0, 0, 0, 0); STG(0, 0, 1, 0);
  STG(1, 1, 0, 1); STG(1, 1, 1, 1);
  VM4(); BAR();   // oldest 8 = buf0 landed; buf1.B may stay in flight

  for (int t = 0; t < nt; ++t) {
    const bool pf = (t < nt - 1);
    // ---- K-tile 2t (buf0). quadrant order (0,0)(0,1)(1,1)(1,0)
    // ph1: stage buf1.A-h0 (K 2t+1)
    LDA8(a, 0, 0); LDB4(b0, 0, 0);
    STG(1, 0, 0, 2 * t + 1);
    BAR(); MFMA16(0, 0, a, b0); BAR();
    // ph2: stage buf1.A-h1         (buf0.B dead after this phase)
    LDB4(b1, 0, 1);
    STG(1, 0, 1, 2 * t + 1);
    BAR(); MFMA16(0, 1, a, b1); BAR();
    // ph3: stage buf0.B-h0 (K 2t+2) — region dead since ph2
    LDA8(a, 0, 1);
    if (pf) STG(0, 1, 0, 2 * t + 2);
    BAR(); MFMA16(1, 1, a, b1); BAR();
    // ph4: stage buf0.B-h1; wait for buf1 (oldest 8 of 12)
    if (pf) STG(0, 1, 1, 2 * t + 2);
    BAR(); MFMA16(1, 0, a, b0);
    if (pf) VM4(); else VM0();
    BAR();
    // ---- K-tile 2t+1 (buf1)
    // ph5: stage buf0.A-h0 (K 2t+2) — buf0.A dead since ph3
    LDA8(a, 1, 0); LDB4(b0, 1, 0);
    if (pf) STG(0, 0, 0, 2 * t + 2);
    BAR(); MFMA16(0, 0, a, b0); BAR();
    // ph6: stage buf0.A-h1
    LDB4(b1, 1, 1);
    if (pf) STG(0, 0, 1, 2 * t + 2);
    BAR(); MFMA16(0, 1, a, b1); BAR();
    // ph7: stage buf1.B-h0 (K 2t+3) — buf1.B dead after ph6
    LDA8(a, 1, 1);
    if (pf) STG(1, 1, 0, 2 * t + 3);
    BAR(); MFMA16(1, 1, a, b1); BAR();
    // ph8: stage buf1.B-h1; wait for buf0 (oldest 8 of 12)
    if (pf) STG(1, 1, 1, 2 * t + 3);
    BAR(); MFMA16(1, 0, a, b0);
    if (pf) VM4();
    BAR();
  }

  const int orow = row0 + wr * 128 + ((lane >> 4) << 2);
  const int ocol = col0 + wc * 64 + (lane & 15);
  if (MODE == 0) {
    unsigned short* out = (unsigned short*)outv + (long long)z * oZ;
    #pragma unroll
    for (int m = 0; m < 8; ++m)
      #pragma unroll
      for (int r = 0; r < 4; ++r) {
        const int rg = orow + m * 16 + r;
        #pragma unroll
        for (int n = 0; n < 4; ++n)
          out[(long long)rg * ldo + ocol + n * 16] = f2b(acc[m][n][r]);
      }
  } else {
    unsigned short* out = (unsigned short*)outv + (long long)z * oZ;
    #pragma unroll
    for (int m = 0; m < 8; ++m)
      #pragma unroll
      for (int r = 0; r < 4; ++r) {
        const int rg = orow + m * 16 + r;
        float rs = 0.f;
        #pragma unroll
        for (int n = 0; n < 4; ++n) {
          const int cg = ocol + n * 16;
          float p = (cg > rg) ? 0.0f : __expf(acc[m][n][r] * 0.03125f);
          rs += p;
          out[(long long)rg * ldo + cg] = f2b(p);
        }
        #pragma unroll
        for (int off = 1; off < 16; off <<= 1) rs += __shfl_xor(rs, off);
        if ((lane & 15) == 0) atomicAdd(&sums[(long long)z * M + rg], rs);
      }
  }
}

// ==================== 128x128 2-phase GEMM (PV only) ====================
// MODE 2: fp32 out scaled by 1/sums[row], K-loop bounded causally.
template<int MODE>
__global__ __launch_bounds__(256) void gemm_bt(
    const unsigned short* __restrict__ A, const unsigned short* __restrict__ Bt,
    void* __restrict__ outv, float* __restrict__ sums,
    int M, int N, int K,
    long long aZ, long long bZ, long long oZ,
    int lda, int ldb, int ldo)
{
  const int z = blockIdx.z;
  const int row0 = blockIdx.y * 128;
  const int col0 = blockIdx.x * 128;

  const unsigned short* Az = A + (long long)z * aZ;
  const unsigned short* Bz = Bt + (long long)z * bZ;

  __shared__ __align__(16) char lds[32768];

  const int tid = threadIdx.x;
  const int wave = tid >> 6;
  const int lane = tid & 63;
  const int wr = wave >> 1, wc = wave & 1;

  const int srow = lane >> 3;
  const int sgrp = (lane & 7) ^ srow;

  const int rA = wr * 64 + (lane & 15);
  const int cB = wc * 64 + (lane & 15);
  const int kb = (lane >> 4) * 16;
  const int xorA = (rA & 7) << 4;
  const int xorB = (cB & 7) << 4;

  f32x4 acc[4][4];
  #pragma unroll
  for (int m = 0; m < 4; ++m)
    #pragma unroll
    for (int n = 0; n < 4; ++n) acc[m][n] = (f32x4)0.0f;

  int kEnd = K;
  if (MODE == 2) kEnd = min(K, row0 + 128);
  const int nkt = kEnd >> 6;

  for (int kt = 0; kt < nkt; ++kt) {
    const int kc = kt * 64;
    #pragma unroll
    for (int i = 0; i < 4; ++i) {
      const int ci = wave * 4 + i;
      gload16(Az + (long long)(row0 + ci * 8 + srow) * lda + kc + sgrp * 8,
              lds + ci * 1024);
      gload16(Bz + (long long)(col0 + ci * 8 + srow) * ldb + kc + sgrp * 8,
              lds + 16384 + ci * 1024);
    }
    __syncthreads();
    #pragma unroll
    for (int ks = 0; ks < 2; ++ks) {
      short8 af[4], bfr[4];
      #pragma unroll
      for (int m = 0; m < 4; ++m)
        af[m] = *(const short8*)(lds + (rA + m * 16) * 128 + ((ks * 64 + kb) ^ xorA));
      #pragma unroll
      for (int n = 0; n < 4; ++n)
        bfr[n] = *(const short8*)(lds + 16384 + (cB + n * 16) * 128 + ((ks * 64 + kb) ^ xorB));
      #pragma unroll
      for (int m = 0; m < 4; ++m)
        #pragma unroll
        for (int n = 0; n < 4; ++n)
          acc[m][n] = __builtin_amdgcn_mfma_f32_16x16x32_bf16(af[m], bfr[n], acc[m][n], 0, 0, 0);
    }
    __syncthreads();
  }

  const int orow = row0 + wr * 64 + ((lane >> 4) << 2);
  const int ocol = col0 + wc * 64 + (lane & 15);
  float* out = (float*)outv + (long long)z * oZ;
  const float* sz = sums + (long long)z * M;
  #pragma unroll
  for (int m = 0; m < 4; ++m)
    #pragma unroll
    for (int r = 0; r < 4; ++r) {
      const int rg = orow + m * 16 + r;
      const float iv = 1.0f / sz[rg];
      #pragma unroll
      for (int n = 0; n < 4; ++n)
        out[(long long)rg * ldo + ocol + n * 16] = acc[m][n][r] * iv;
    }
}

// fp32 -> bf16 convert, 4 elems/thread
__global__ __launch_bounds__(256) void cvt_x(const float* __restrict__ in,
                                             unsigned short* __restrict__ out, int n4) {
  int i = blockIdx.x * 256 + threadIdx.x;
  if (i >= n4) return;
  const float4 f = ((const float4*)in)[i];
  union { unsigned short u[4]; uint2 v; } o;
  o.u[0] = f2b(f.x); o.u[1] = f2b(f.y); o.u[2] = f2b(f.z); o.u[3] = f2b(f.w);
  ((uint2*)out)[i] = o.v;
}

// W [1024][1024] fp32 -> Wt bf16 transposed; 3 matrices (z) into contiguous [3072][1024]
__global__ __launch_bounds__(256) void cvt_w(
    const float* __restrict__ W0, const float* __restrict__ W1, const float* __restrict__ W2,
    unsigned short* __restrict__ O) {
  const float* W = blockIdx.z == 0 ? W0 : (blockIdx.z == 1 ? W1 : W2);
  unsigned short* Oz = O + (long long)blockIdx.z * 1024 * 1024;
  __shared__ float t[32][33];
  const int tx = threadIdx.x, ty = threadIdx.y;
  const int x = blockIdx.x * 32 + tx;
  const int y0 = blockIdx.y * 32;
  #pragma unroll
  for (int i = 0; i < 4; ++i)
    t[ty + i * 8][tx] = W[(long long)(y0 + ty + i * 8) * 1024 + x];
  __syncthreads();
  const int xo = blockIdx.y * 32 + tx;
  const int yo0 = blockIdx.x * 32;
  #pragma unroll
  for (int i = 0; i < 4; ++i)
    Oz[(long long)(yo0 + ty + i * 8) * 1024 + xo] = f2b(t[tx][ty + i * 8]);
}

// Vt[b][d][t] = QKV[b*2048+t][2048+d]
__global__ __launch_bounds__(256) void vtrans(const unsigned short* __restrict__ QKV,
                                              unsigned short* __restrict__ Vt) {
  __shared__ unsigned short t[32][33];
  const int tx = threadIdx.x, ty = threadIdx.y;  // 32x8
  const int b = blockIdx.z;
  const int t0 = blockIdx.x * 32;
  const int d0 = blockIdx.y * 32;
  #pragma unroll
  for (int i = 0; i < 4; ++i)
    t[ty + i * 8][tx] = QKV[(long long)(b * 2048 + t0 + ty + i * 8) * 3072 + 2048 + d0 + tx];
  __syncthreads();
  #pragma unroll
  for (int i = 0; i < 4; ++i)
    Vt[((long long)b * 1024 + d0 + ty + i * 8) * 2048 + t0 + tx] = t[tx][ty + i * 8];
}

extern "C" void kernel_launch(void* const* d_in, const int* in_sizes, int n_in,
                              void* d_out, int out_size, void* d_ws, size_t ws_size,
                              hipStream_t stream) {
  (void)in_sizes; (void)n_in; (void)out_size; (void)ws_size;
  const float* x  = (const float*)d_in[0];
  const float* Wq = (const float*)d_in[1];
  const float* Wk = (const float*)d_in[2];
  const float* Wv = (const float*)d_in[3];
  float* out = (float*)d_out;

  char* ws = (char*)d_ws;
  unsigned short* xb  = (unsigned short*)(ws);               // 8192x1024 bf16
  unsigned short* Wt  = (unsigned short*)(ws + 16777216);    // 3072x1024 bf16
  unsigned short* P   = (unsigned short*)(ws);               // 4x2048x2048 bf16 (reuses xb+Wt)
  unsigned short* QKV = (unsigned short*)(ws + 33554432);    // 8192x3072 bf16
  unsigned short* Vt  = (unsigned short*)(ws + 83886080);    // 4x1024x2048 bf16
  float*          sums = (float*)(ws + 100663296);           // 4x2048 fp32

  hipMemsetAsync(sums, 0, 4 * 2048 * sizeof(float), stream);

  // 1. dtype conversions
  cvt_x<<<8192, 256, 0, stream>>>(x, xb, 2097152);
  cvt_w<<<dim3(32, 32, 3), dim3(32, 8), 0, stream>>>(Wq, Wk, Wv, Wt);

  // 2. fused QKV = x . Wt^T  [8192][3072]  (8-phase 256^2, deep pipeline)
  gemm8<0><<<dim3(12, 32, 1), 512, 0, stream>>>(xb, Wt, QKV, nullptr,
      8192, 3072, 1024, 0, 0, 0, 1024, 1024, 3072);

  // 3. V section -> Vt [b][1024][2048]
  vtrans<<<dim3(64, 32, 4), dim3(32, 8), 0, stream>>>(QKV, Vt);

  // 4. P = exp((Q K^T)/32) causal, unnormalized bf16 + rowsums  (8-phase 256^2)
  gemm8<1><<<dim3(8, 8, 4), 512, 0, stream>>>(QKV, QKV + 1024, P, sums,
      2048, 2048, 1024, (long long)2048 * 3072, (long long)2048 * 3072,
      (long long)2048 * 2048, 3072, 3072, 2048);

  // 5. context = (P Vt^T) / rowsum  (fp32 out, causal K-bound)
  gemm_bt<2><<<dim3(8, 16, 4), 256, 0, stream>>>(P, Vt, out, sums,
      2048, 1024, 2048, (long long)2048 * 2048, (long long)1024 * 2048,
      (long long)2048 * 1024, 2048, 2048, 1024);
}